// Round 9
// baseline (318.259 us; speedup 1.0000x reference)
//
#include <hip/hip_runtime.h>

#define NN 50000
#define NE 800000
#define NL 200000
#define FEAT 128
#define HID 32
#define HEADS 8
#define H1 256   // HEADS*HID
#define CAP 64   // per-node CSR bucket capacity (P(deg>64) ~ 1e-20 for Poisson(16))
#define NB 32    // nodes per block in k_p12

using u32 = unsigned int;

__device__ __forceinline__ float bflo(u32 v) { return __uint_as_float(v << 16); }
__device__ __forceinline__ float bfhi(u32 v) { return __uint_as_float(v & 0xffff0000u); }
__device__ __forceinline__ u32 packbf(float a, float b) {
  u32 ua = __float_as_uint(a), ub = __float_as_uint(b);
  ua += 0x7fffu + ((ua >> 16) & 1u);   // RNE
  ub += 0x7fffu + ((ub >> 16) & 1u);
  return (ua >> 16) | (ub & 0xffff0000u);
}

// ---------------------------------------------------------------------------
// v-vector precompute (collapses dst-side [N,256] GEMMs into matvecs)
// ---------------------------------------------------------------------------
__global__ __launch_bounds__(256) void k_vprep(
    const float* __restrict__ w1s, const float* __restrict__ w1d,
    const float* __restrict__ a1s, const float* __restrict__ a1d,
    const float* __restrict__ w2s, const float* __restrict__ w2d,
    const float* __restrict__ a2s, const float* __restrict__ a2d,
    float* __restrict__ v1s, float* __restrict__ v1d,
    float* __restrict__ v2s, float* __restrict__ v2d) {
  int tid = threadIdx.x;
  int k = tid >> 3, h = tid & 7;
  float ss = 0.f, sd = 0.f;
  for (int c = 0; c < 32; ++c) {
    ss += w1s[k * H1 + h * 32 + c] * a1s[h * 32 + c];
    sd += w1d[k * H1 + h * 32 + c] * a1d[h * 32 + c];
  }
  v1s[k * 8 + h] = ss;
  v1d[k * 8 + h] = sd;
  float s2 = 0.f, d2 = 0.f;
  for (int c = 0; c < 32; ++c) {
    s2 += w2s[tid * 32 + c] * a2s[c];
    d2 += w2d[tid * 32 + c] * a2d[c];
  }
  v2s[tid] = s2;
  v2d[tid] = d2;
}

// ---------------------------------------------------------------------------
// Bucketed CSR fill
// ---------------------------------------------------------------------------
__global__ void k_fill(const int* __restrict__ src, const int* __restrict__ dst,
                       int* __restrict__ cnt, int* __restrict__ csr) {
  int e = blockIdx.x * 256 + threadIdx.x;
  if (e >= NE) return;
  int d = dst[e];
  int slot = atomicAdd(&cnt[d], 1);
  if (slot < CAP) csr[(size_t)d * CAP + slot] = src[e];
}

// ---------------------------------------------------------------------------
// Layer-1 prep: h0 = x@lin_w+lin_b (LDS), write h0b (bf16, 3.2MB) + as1/ad1.
// ---------------------------------------------------------------------------
__global__ __launch_bounds__(256) void k_l1(
    const float* __restrict__ x, const float* __restrict__ lin_w,
    const float* __restrict__ lin_b, const float* __restrict__ v1s,
    const float* __restrict__ v1d, u32* __restrict__ h0b,
    float* __restrict__ as1, float* __restrict__ ad1) {
  __shared__ float wl[FEAT * HID];   // 16KB
  __shared__ float xl[32 * FEAT];    // 16KB
  __shared__ float h0l[32 * HID];    // 4KB
  __shared__ float vsl[HID * 8], vdl[HID * 8], bl[HID];
  int tid = threadIdx.x;
  for (int i = tid; i < (FEAT * HID) / 4; i += 256)
    ((float4*)wl)[i] = ((const float4*)lin_w)[i];
  vsl[tid] = v1s[tid];
  vdl[tid] = v1d[tid];
  if (tid < HID) bl[tid] = lin_b[tid];
  int n0 = blockIdx.x * 32;
  for (int i = tid; i < (32 * FEAT) / 4; i += 256) {
    int n = n0 + (i >> 5);
    ((float4*)xl)[i] = (n < NN) ? ((const float4*)x)[(size_t)n * 32 + (i & 31)]
                                : make_float4(0.f, 0.f, 0.f, 0.f);
  }
  __syncthreads();
  {
    int nl = tid >> 5, c = tid & 31;
    float acc[4] = {0.f, 0.f, 0.f, 0.f};
    for (int k = 0; k < FEAT; ++k) {
      float wv = wl[k * HID + c];
#pragma unroll
      for (int j = 0; j < 4; ++j) acc[j] += xl[(nl + 8 * j) * FEAT + k] * wv;
    }
#pragma unroll
    for (int j = 0; j < 4; ++j) h0l[(nl + 8 * j) * HID + c] = acc[j] + bl[c];
  }
  __syncthreads();
  for (int i = tid; i < 512; i += 256) {
    int nl = i >> 4, cp = i & 15;
    int n = n0 + nl;
    if (n < NN)
      h0b[(size_t)n * 16 + cp] =
          packbf(h0l[nl * 32 + 2 * cp], h0l[nl * 32 + 2 * cp + 1]);
  }
  {
    int nl = tid >> 3, h = tid & 7;
    int n = n0 + nl;
    if (n < NN) {
      float ss = 0.f, sd = 0.f;
#pragma unroll
      for (int k = 0; k < HID; ++k) {
        float hv = h0l[nl * HID + k];
        ss += hv * vsl[k * 8 + h];
        sd += hv * vdl[k * 8 + h];
      }
      as1[(size_t)n * 8 + h] = ss;
      ad1[(size_t)n * 8 + h] = sd;
    }
  }
}

// ---------------------------------------------------------------------------
// Edge aggregation in h0-space. Wave per node, NO LDS, NO cross-lane ops in
// the loop. Lane = (head h = lane>>3, col-quarter cq = lane&7): each lane
// computes e for its OWN head (8x redundant exp -- cheap) and accumulates
// its 4 columns (one uint2 = 4 bf16) into 4 private registers.
// Final: 2 packed u32 stores per lane; den by cq==0 lanes. ~30 VGPR.
// ---------------------------------------------------------------------------
__global__ __launch_bounds__(256) void k_aggE(
    const int* __restrict__ cnt, const int* __restrict__ csr,
    const u32* __restrict__ h0b, const float* __restrict__ as1,
    const float* __restrict__ ad1, u32* __restrict__ aggb,
    float* __restrict__ den1) {
  int tid = threadIdx.x;
  int w = tid >> 6, lane = tid & 63;
  int h = lane >> 3, cq = lane & 7;
  int n = blockIdx.x * 4 + w;          // grid = NN/4 exactly
  const uint2* h0b2 = (const uint2*)h0b;
  float adreg = ad1[(size_t)n * 8 + h];
  float a0 = 0.f, a1 = 0.f, a2 = 0.f, a3 = 0.f, den = 0.f;
  int m = min(cnt[n], CAP);
  const int* cs = csr + (size_t)n * CAP;
  int j = 0;
  for (; j + 1 < m; j += 2) {
    int sA = cs[j], sB = cs[j + 1];
    float aA = as1[(size_t)sA * 8 + h] + adreg;
    aA = aA > 0.f ? aA : 0.2f * aA;
    float aB = as1[(size_t)sB * 8 + h] + adreg;
    aB = aB > 0.f ? aB : 0.2f * aB;
    float eA = __expf(aA), eB = __expf(aB);
    uint2 wA = h0b2[(size_t)sA * 8 + cq];
    uint2 wB = h0b2[(size_t)sB * 8 + cq];
    den += eA + eB;
    a0 += eA * bflo(wA.x) + eB * bflo(wB.x);
    a1 += eA * bfhi(wA.x) + eB * bfhi(wB.x);
    a2 += eA * bflo(wA.y) + eB * bflo(wB.y);
    a3 += eA * bfhi(wA.y) + eB * bfhi(wB.y);
  }
  if (j < m) {
    int sA = cs[j];
    float aA = as1[(size_t)sA * 8 + h] + adreg;
    aA = aA > 0.f ? aA : 0.2f * aA;
    float eA = __expf(aA);
    uint2 wA = h0b2[(size_t)sA * 8 + cq];
    den += eA;
    a0 += eA * bflo(wA.x);
    a1 += eA * bfhi(wA.x);
    a2 += eA * bflo(wA.y);
    a3 += eA * bfhi(wA.y);
  }
  if (cq == 0) den1[(size_t)n * 8 + h] = den;
  ((uint2*)aggb)[(size_t)n * 64 + h * 8 + cq] =
      make_uint2(packbf(a0, a1), packbf(a2, a3));
}

// ---------------------------------------------------------------------------
// P1+P2 projections. Weights in registers; agg + h1 staged as bf16 in LDS
// (37KB total -> 4 blocks/CU). 4 independent FMA chains per output.
// ---------------------------------------------------------------------------
__global__ __launch_bounds__(256) void k_p12(
    const u32* __restrict__ aggb, const float* __restrict__ den1,
    const float* __restrict__ w1s, const float* __restrict__ b1,
    const float* __restrict__ w2s, const float* __restrict__ v2s,
    const float* __restrict__ v2d, u32* __restrict__ xs2b,
    float* __restrict__ as2, float* __restrict__ ad2) {
  __shared__ u32 aggl[NB * 128];      // 16KB; reused as part[] after P1
  __shared__ u32 sh1b[NB * 130];      // 16.6KB bf16 h1 pairs (pad 130)
  __shared__ float denl[NB * 8];
  __shared__ float v2sl[H1], v2dl[H1];
  int tid = threadIdx.x;
  int n0 = blockIdx.x * NB;
  int h = tid >> 5, c = tid & 31;
  float w1reg[32], w2reg[32];
#pragma unroll
  for (int k = 0; k < 32; ++k) w1reg[k] = w1s[k * H1 + tid];
#pragma unroll
  for (int k = 0; k < 32; ++k) w2reg[k] = w2s[h * 1024 + k * 32 + c];
  float b1reg = b1[tid];
  v2sl[tid] = v2s[tid];
  v2dl[tid] = v2d[tid];
  for (int q = 0; q < 4; ++q) {
    int i = tid + 256 * q;
    int nn = n0 + (i >> 5);
    ((uint4*)aggl)[i] = (nn < NN) ? ((const uint4*)aggb)[(size_t)n0 * 32 + i]
                                  : make_uint4(0u, 0u, 0u, 0u);
  }
  {
    int nn = n0 + (tid >> 3);
    denl[tid] = (nn < NN) ? den1[(size_t)nn * 8 + (tid & 7)] : 1.f;
  }
  __syncthreads();
  // P1: h1 = relu(agg@W1s/den + b1), bf16-packed into sh1b
  for (int n = 0; n < NB; ++n) {
    const u32* ag = &aggl[n * 128 + h * 16];
    float o0 = 0.f, o1 = 0.f, o2 = 0.f, o3 = 0.f;
#pragma unroll
    for (int kp = 0; kp < 4; ++kp) {
      u32 v0 = ag[kp], v1 = ag[kp + 4], v2v = ag[kp + 8], v3 = ag[kp + 12];
      o0 += bflo(v0) * w1reg[2 * kp] + bfhi(v0) * w1reg[2 * kp + 1];
      o1 += bflo(v1) * w1reg[2 * kp + 8] + bfhi(v1) * w1reg[2 * kp + 9];
      o2 += bflo(v2v) * w1reg[2 * kp + 16] + bfhi(v2v) * w1reg[2 * kp + 17];
      o3 += bflo(v3) * w1reg[2 * kp + 24] + bfhi(v3) * w1reg[2 * kp + 25];
    }
    float out = (o0 + o1) + (o2 + o3);
    float inv = 1.f / (denl[n * 8 + h] + 1e-16f);
    float r = out * inv + b1reg;
    r = r > 0.f ? r : 0.f;
    float other = __shfl_xor(r, 1);
    if (!(c & 1)) sh1b[n * 130 + h * 16 + (c >> 1)] = packbf(r, other);
  }
  __syncthreads();
  // P2: xs2 partials per wave (k range = h*32..h*32+31 per thread)
  float* part = (float*)aggl;         // [4][NB][32]
  int wv = tid >> 6, lane = tid & 63;
  for (int n = 0; n < NB; ++n) {
    const u32* hp = &sh1b[n * 130 + h * 16];
    float p0 = 0.f, p1 = 0.f, p2 = 0.f, p3 = 0.f;
#pragma unroll
    for (int kp = 0; kp < 4; ++kp) {
      u32 v0 = hp[kp], v1 = hp[kp + 4], v2v = hp[kp + 8], v3 = hp[kp + 12];
      p0 += bflo(v0) * w2reg[2 * kp] + bfhi(v0) * w2reg[2 * kp + 1];
      p1 += bflo(v1) * w2reg[2 * kp + 8] + bfhi(v1) * w2reg[2 * kp + 9];
      p2 += bflo(v2v) * w2reg[2 * kp + 16] + bfhi(v2v) * w2reg[2 * kp + 17];
      p3 += bflo(v3) * w2reg[2 * kp + 24] + bfhi(v3) * w2reg[2 * kp + 25];
    }
    float pp = (p0 + p1) + (p2 + p3);
    pp += __shfl_xor(pp, 32);
    if (lane < 32) part[wv * (NB * 32) + n * 32 + c] = pp;
  }
  __syncthreads();
#pragma unroll
  for (int q = 0; q < 4; ++q) {
    int slot = tid + 256 * q;
    int nn = slot >> 5, cc = slot & 31;
    float s = part[slot] + part[1024 + slot] + part[2048 + slot] +
              part[3072 + slot];
    float other = __shfl_xor(s, 1);
    int gn = n0 + nn;
    if (gn < NN && !(cc & 1))
      xs2b[(size_t)gn * 16 + (cc >> 1)] = packbf(s, other);
  }
  // v2 dots from bf16 sh1b; bank-rotated reads
  {
    int nn = tid >> 3, kg = tid & 7;
    float ssum = 0.f, dsum = 0.f;
#pragma unroll
    for (int q = 0; q < 16; ++q) {
      int qq = (q + 2 * kg) & 15;
      u32 v = sh1b[nn * 130 + kg * 16 + qq];
      int ki = kg * 32 + 2 * qq;
      ssum += bflo(v) * v2sl[ki] + bfhi(v) * v2sl[ki + 1];
      dsum += bflo(v) * v2dl[ki] + bfhi(v) * v2dl[ki + 1];
    }
    ssum += __shfl_xor(ssum, 1);
    dsum += __shfl_xor(dsum, 1);
    ssum += __shfl_xor(ssum, 2);
    dsum += __shfl_xor(dsum, 2);
    ssum += __shfl_xor(ssum, 4);
    dsum += __shfl_xor(dsum, 4);
    int gn = n0 + nn;
    if (kg == 0 && gn < NN) {
      as2[gn] = ssum;
      ad2[gn] = dsum;
    }
  }
}

// ---------------------------------------------------------------------------
// conv2 aggregate: 8 nodes/block; xs2b 3.2MB L2-resident gather. h2 fp32.
// ---------------------------------------------------------------------------
__global__ __launch_bounds__(256) void k_agg2(
    const int* __restrict__ cnt, const int* __restrict__ csr,
    const u32* __restrict__ xs2b, const float* __restrict__ as2,
    const float* __restrict__ ad2, const float* __restrict__ b2,
    float* __restrict__ h2) {
  int tid = threadIdx.x;
  int n = blockIdx.x * 8 + (tid >> 5);
  int sub = tid & 31, g = sub >> 4, l = sub & 15;
  if (n >= NN) return;
  float adn = ad2[n];
  int m = min(cnt[n], CAP);
  const int* cs = csr + (size_t)n * CAP;
  float a0 = 0.f, a1v = 0.f, ea = 0.f;
  int j = g;
  for (; j + 2 < m; j += 4) {
    int sA = cs[j], sB = cs[j + 2];
    float alA = as2[sA] + adn; alA = alA > 0.f ? alA : 0.2f * alA;
    float alB = as2[sB] + adn; alB = alB > 0.f ? alB : 0.2f * alB;
    float eA = __expf(alA), eB = __expf(alB);
    u32 vA = xs2b[(size_t)sA * 16 + l], vB = xs2b[(size_t)sB * 16 + l];
    a0 += bflo(vA) * eA + bflo(vB) * eB;
    a1v += bfhi(vA) * eA + bfhi(vB) * eB;
    ea += eA + eB;
  }
  for (; j < m; j += 2) {
    int s = cs[j];
    float al = as2[s] + adn; al = al > 0.f ? al : 0.2f * al;
    float ee = __expf(al);
    u32 v = xs2b[(size_t)s * 16 + l];
    a0 += bflo(v) * ee;
    a1v += bfhi(v) * ee;
    ea += ee;
  }
  a0 += __shfl_xor(a0, 16);
  a1v += __shfl_xor(a1v, 16);
  ea += __shfl_xor(ea, 16);
  if (g == 0) {
    float inv = 1.f / (ea + 1e-16f);
    float o0 = a0 * inv + b2[2 * l];
    float o1 = a1v * inv + b2[2 * l + 1];
    ((float2*)h2)[(size_t)n * 16 + l] = make_float2(o0, o1);
  }
}

// ---------------------------------------------------------------------------
// classifier: 8 lanes per label, float4 loads, shfl reduce
// ---------------------------------------------------------------------------
__global__ __launch_bounds__(256) void k_pred(const int* __restrict__ eli,
                                              const float* __restrict__ h2,
                                              float* __restrict__ out) {
  int gid = blockIdx.x * 256 + threadIdx.x;
  int lab = gid >> 3, q = gid & 7;
  if (lab >= NL) return;
  int a = eli[lab], b = eli[NL + lab];
  float4 va = ((const float4*)(h2 + (size_t)a * HID))[q];
  float4 vb = ((const float4*)(h2 + (size_t)b * HID))[q];
  float s = va.x * vb.x + va.y * vb.y + va.z * vb.z + va.w * vb.w;
  s += __shfl_xor(s, 1);
  s += __shfl_xor(s, 2);
  s += __shfl_xor(s, 4);
  if (q == 0) out[lab] = s;
}

extern "C" void kernel_launch(void* const* d_in, const int* in_sizes, int n_in,
                              void* d_out, int out_size, void* d_ws, size_t ws_size,
                              hipStream_t stream) {
  const float* x     = (const float*)d_in[0];
  const int*   ei    = (const int*)d_in[1];
  const int*   eli   = (const int*)d_in[2];
  const float* lin_w = (const float*)d_in[3];
  const float* lin_b = (const float*)d_in[4];
  const float* w1s   = (const float*)d_in[5];
  const float* w1d   = (const float*)d_in[6];
  const float* a1s   = (const float*)d_in[7];
  const float* a1d   = (const float*)d_in[8];
  const float* b1    = (const float*)d_in[9];
  const float* w2s   = (const float*)d_in[10];
  const float* w2d   = (const float*)d_in[11];
  const float* a2s   = (const float*)d_in[12];
  const float* a2d   = (const float*)d_in[13];
  const float* b2    = (const float*)d_in[14];
  float* out = (float*)d_out;

  char* p = (char*)d_ws;
  auto take = [&](size_t bytes) {
    char* r = p;
    p += (bytes + 255) & ~(size_t)255;
    return r;
  };
  int*   cnt  = (int*)take((size_t)NN * 4);           // zeroed per call
  int*   csr  = (int*)take((size_t)NN * CAP * 4);     // 12.8MB
  u32*   h0b  = (u32*)take((size_t)NN * 16 * 4);      // 3.2MB (bf16 pairs)
  float* as1  = (float*)take((size_t)NN * 8 * 4);
  float* ad1  = (float*)take((size_t)NN * 8 * 4);
  u32*   aggb = (u32*)take((size_t)NN * 128 * 4);     // 25.6MB (bf16 pairs)
  float* den1 = (float*)take((size_t)NN * 8 * 4);     // 1.6MB
  u32*   xs2b = (u32*)take((size_t)NN * 16 * 4);      // 3.2MB
  float* as2  = (float*)take((size_t)NN * 4);
  float* ad2  = (float*)take((size_t)NN * 4);
  float* h2   = (float*)take((size_t)NN * HID * 4);   // fp32
  float* v1s  = (float*)take(256 * 4);
  float* v1d  = (float*)take(256 * 4);
  float* v2s  = (float*)take(256 * 4);
  float* v2d  = (float*)take(256 * 4);

  const int* esrc = ei;
  const int* edst = ei + NE;

  hipMemsetAsync(cnt, 0, (size_t)NN * 4, stream);
  k_vprep<<<1, 256, 0, stream>>>(w1s, w1d, a1s, a1d, w2s, w2d, a2s, a2d,
                                 v1s, v1d, v2s, v2d);
  k_fill<<<(NE + 255) / 256, 256, 0, stream>>>(esrc, edst, cnt, csr);
  k_l1<<<(NN + 31) / 32, 256, 0, stream>>>(x, lin_w, lin_b, v1s, v1d,
                                           h0b, as1, ad1);
  k_aggE<<<NN / 4, 256, 0, stream>>>(cnt, csr, h0b, as1, ad1, aggb, den1);
  k_p12<<<(NN + NB - 1) / NB, 256, 0, stream>>>(aggb, den1, w1s, b1, w2s,
                                                v2s, v2d, xs2b, as2, ad2);
  k_agg2<<<(NN + 7) / 8, 256, 0, stream>>>(cnt, csr, xs2b, as2, ad2, b2, h2);
  k_pred<<<(NL * 8 + 255) / 256, 256, 0, stream>>>(eli, h2, out);
}

// Round 11
// 314.360 us; speedup vs baseline: 1.0124x; 1.0124x over previous
//
#include <hip/hip_runtime.h>

#define NN 50000
#define NE 800000
#define NL 200000
#define FEAT 128
#define HID 32
#define HEADS 8
#define H1 256   // HEADS*HID
#define CAP 64   // per-node CSR bucket capacity (P(deg>64) ~ 1e-20 for Poisson(16))
#define NB 16    // nodes per block in k_p12 (50000 = 3125*16, no tail)
#define PAD 264  // sh1 row stride: mult of 4 (float4-aligned), 264%32=8

using u32 = unsigned int;

__device__ __forceinline__ float bflo(u32 v) { return __uint_as_float(v << 16); }
__device__ __forceinline__ float bfhi(u32 v) { return __uint_as_float(v & 0xffff0000u); }
__device__ __forceinline__ u32 packbf(float a, float b) {
  u32 ua = __float_as_uint(a), ub = __float_as_uint(b);
  ua += 0x7fffu + ((ua >> 16) & 1u);   // RNE
  ub += 0x7fffu + ((ub >> 16) & 1u);
  return (ua >> 16) | (ub & 0xffff0000u);
}

// ---------------------------------------------------------------------------
// v-vector precompute (collapses dst-side [N,256] GEMMs into matvecs)
// ---------------------------------------------------------------------------
__global__ __launch_bounds__(256) void k_vprep(
    const float* __restrict__ w1s, const float* __restrict__ w1d,
    const float* __restrict__ a1s, const float* __restrict__ a1d,
    const float* __restrict__ w2s, const float* __restrict__ w2d,
    const float* __restrict__ a2s, const float* __restrict__ a2d,
    float* __restrict__ v1s, float* __restrict__ v1d,
    float* __restrict__ v2s, float* __restrict__ v2d) {
  int tid = threadIdx.x;
  int k = tid >> 3, h = tid & 7;
  float ss = 0.f, sd = 0.f;
  for (int c = 0; c < 32; ++c) {
    ss += w1s[k * H1 + h * 32 + c] * a1s[h * 32 + c];
    sd += w1d[k * H1 + h * 32 + c] * a1d[h * 32 + c];
  }
  v1s[k * 8 + h] = ss;
  v1d[k * 8 + h] = sd;
  float s2 = 0.f, d2 = 0.f;
  for (int c = 0; c < 32; ++c) {
    s2 += w2s[tid * 32 + c] * a2s[c];
    d2 += w2d[tid * 32 + c] * a2d[c];
  }
  v2s[tid] = s2;
  v2d[tid] = d2;
}

// ---------------------------------------------------------------------------
// Bucketed CSR fill
// ---------------------------------------------------------------------------
__global__ void k_fill(const int* __restrict__ src, const int* __restrict__ dst,
                       int* __restrict__ cnt, int* __restrict__ csr) {
  int e = blockIdx.x * 256 + threadIdx.x;
  if (e >= NE) return;
  int d = dst[e];
  int slot = atomicAdd(&cnt[d], 1);
  if (slot < CAP) csr[(size_t)d * CAP + slot] = src[e];
}

// ---------------------------------------------------------------------------
// Layer-1 prep: h0 = x@lin_w+lin_b (LDS), write h0b (bf16, 3.2MB) + as1/ad1.
// ---------------------------------------------------------------------------
__global__ __launch_bounds__(256) void k_l1(
    const float* __restrict__ x, const float* __restrict__ lin_w,
    const float* __restrict__ lin_b, const float* __restrict__ v1s,
    const float* __restrict__ v1d, u32* __restrict__ h0b,
    float* __restrict__ as1, float* __restrict__ ad1) {
  __shared__ float wl[FEAT * HID];   // 16KB
  __shared__ float xl[32 * FEAT];    // 16KB
  __shared__ float h0l[32 * HID];    // 4KB
  __shared__ float vsl[HID * 8], vdl[HID * 8], bl[HID];
  int tid = threadIdx.x;
  for (int i = tid; i < (FEAT * HID) / 4; i += 256)
    ((float4*)wl)[i] = ((const float4*)lin_w)[i];
  vsl[tid] = v1s[tid];
  vdl[tid] = v1d[tid];
  if (tid < HID) bl[tid] = lin_b[tid];
  int n0 = blockIdx.x * 32;
  for (int i = tid; i < (32 * FEAT) / 4; i += 256) {
    int n = n0 + (i >> 5);
    ((float4*)xl)[i] = (n < NN) ? ((const float4*)x)[(size_t)n * 32 + (i & 31)]
                                : make_float4(0.f, 0.f, 0.f, 0.f);
  }
  __syncthreads();
  {
    int nl = tid >> 5, c = tid & 31;
    float acc[4] = {0.f, 0.f, 0.f, 0.f};
    for (int k = 0; k < FEAT; ++k) {
      float wv = wl[k * HID + c];
#pragma unroll
      for (int j = 0; j < 4; ++j) acc[j] += xl[(nl + 8 * j) * FEAT + k] * wv;
    }
#pragma unroll
    for (int j = 0; j < 4; ++j) h0l[(nl + 8 * j) * HID + c] = acc[j] + bl[c];
  }
  __syncthreads();
  for (int i = tid; i < 512; i += 256) {
    int nl = i >> 4, cp = i & 15;
    int n = n0 + nl;
    if (n < NN)
      h0b[(size_t)n * 16 + cp] =
          packbf(h0l[nl * 32 + 2 * cp], h0l[nl * 32 + 2 * cp + 1]);
  }
  {
    int nl = tid >> 3, h = tid & 7;
    int n = n0 + nl;
    if (n < NN) {
      float ss = 0.f, sd = 0.f;
#pragma unroll
      for (int k = 0; k < HID; ++k) {
        float hv = h0l[nl * HID + k];
        ss += hv * vsl[k * 8 + h];
        sd += hv * vdl[k * 8 + h];
      }
      as1[(size_t)n * 8 + h] = ss;
      ad1[(size_t)n * 8 + h] = sd;
    }
  }
}

// ---------------------------------------------------------------------------
// Edge aggregation in h0-space. Wave per node, no LDS, no cross-lane ops in
// the loop. Lane = (head h = lane>>3, col-quarter cq = lane&7).
// ---------------------------------------------------------------------------
__global__ __launch_bounds__(256) void k_aggE(
    const int* __restrict__ cnt, const int* __restrict__ csr,
    const u32* __restrict__ h0b, const float* __restrict__ as1,
    const float* __restrict__ ad1, u32* __restrict__ aggb,
    float* __restrict__ den1) {
  int tid = threadIdx.x;
  int w = tid >> 6, lane = tid & 63;
  int h = lane >> 3, cq = lane & 7;
  int n = blockIdx.x * 4 + w;          // grid = NN/4 exactly
  const uint2* h0b2 = (const uint2*)h0b;
  float adreg = ad1[(size_t)n * 8 + h];
  float a0 = 0.f, a1 = 0.f, a2 = 0.f, a3 = 0.f, den = 0.f;
  int m = min(cnt[n], CAP);
  const int* cs = csr + (size_t)n * CAP;
  int j = 0;
  for (; j + 1 < m; j += 2) {
    int sA = cs[j], sB = cs[j + 1];
    float aA = as1[(size_t)sA * 8 + h] + adreg;
    aA = aA > 0.f ? aA : 0.2f * aA;
    float aB = as1[(size_t)sB * 8 + h] + adreg;
    aB = aB > 0.f ? aB : 0.2f * aB;
    float eA = __expf(aA), eB = __expf(aB);
    uint2 wA = h0b2[(size_t)sA * 8 + cq];
    uint2 wB = h0b2[(size_t)sB * 8 + cq];
    den += eA + eB;
    a0 += eA * bflo(wA.x) + eB * bflo(wB.x);
    a1 += eA * bfhi(wA.x) + eB * bfhi(wB.x);
    a2 += eA * bflo(wA.y) + eB * bflo(wB.y);
    a3 += eA * bfhi(wA.y) + eB * bfhi(wB.y);
  }
  if (j < m) {
    int sA = cs[j];
    float aA = as1[(size_t)sA * 8 + h] + adreg;
    aA = aA > 0.f ? aA : 0.2f * aA;
    float eA = __expf(aA);
    uint2 wA = h0b2[(size_t)sA * 8 + cq];
    den += eA;
    a0 += eA * bflo(wA.x);
    a1 += eA * bfhi(wA.x);
    a2 += eA * bflo(wA.y);
    a3 += eA * bfhi(wA.y);
  }
  if (cq == 0) den1[(size_t)n * 8 + h] = den;
  ((uint2*)aggb)[(size_t)n * 64 + h * 8 + cq] =
      make_uint2(packbf(a0, a1), packbf(a2, a3));
}

// ---------------------------------------------------------------------------
// P1+P2 projections, v3: no agg LDS staging (uniform global uint4 loads,
// L1-broadcast), fp32 sh1 (no pack/unpack), 4-way FMA chains, NB=16.
// LDS ~27KB -> 5 blocks/CU.
// ---------------------------------------------------------------------------
__global__ __launch_bounds__(256) void k_p12(
    const u32* __restrict__ aggb, const float* __restrict__ den1,
    const float* __restrict__ w1s, const float* __restrict__ b1,
    const float* __restrict__ w2s, const float* __restrict__ v2s,
    const float* __restrict__ v2d, u32* __restrict__ xs2b,
    float* __restrict__ as2, float* __restrict__ ad2) {
  __shared__ float sh1[NB * PAD];      // 16.9KB fp32 h1
  __shared__ float part[4 * NB * 32];  // 8KB xs2 partials
  __shared__ float v2sl[H1], v2dl[H1];
  int tid = threadIdx.x;
  int n0 = blockIdx.x * NB;
  int h = tid >> 5, c = tid & 31;
  float w1reg[32], w2reg[32];
#pragma unroll
  for (int k = 0; k < 32; ++k) w1reg[k] = w1s[k * H1 + tid];
#pragma unroll
  for (int k = 0; k < 32; ++k) w2reg[k] = w2s[h * 1024 + k * 32 + c];
  float b1reg = b1[tid];
  v2sl[tid] = v2s[tid];
  v2dl[tid] = v2d[tid];
  __syncthreads();
  // P1: h1 = relu(agg@W1s/den + b1); agg rows via uniform global loads
  for (int n = 0; n < NB; ++n) {
    int gn = n0 + n;
    const uint4* row = (const uint4*)(aggb + (size_t)gn * 128 + h * 16);
    uint4 r0 = row[0], r1 = row[1], r2 = row[2], r3 = row[3];
    float o0 = 0.f, o1 = 0.f, o2 = 0.f, o3 = 0.f;
    o0 += bflo(r0.x) * w1reg[0] + bfhi(r0.x) * w1reg[1];
    o0 += bflo(r0.y) * w1reg[2] + bfhi(r0.y) * w1reg[3];
    o0 += bflo(r0.z) * w1reg[4] + bfhi(r0.z) * w1reg[5];
    o0 += bflo(r0.w) * w1reg[6] + bfhi(r0.w) * w1reg[7];
    o1 += bflo(r1.x) * w1reg[8] + bfhi(r1.x) * w1reg[9];
    o1 += bflo(r1.y) * w1reg[10] + bfhi(r1.y) * w1reg[11];
    o1 += bflo(r1.z) * w1reg[12] + bfhi(r1.z) * w1reg[13];
    o1 += bflo(r1.w) * w1reg[14] + bfhi(r1.w) * w1reg[15];
    o2 += bflo(r2.x) * w1reg[16] + bfhi(r2.x) * w1reg[17];
    o2 += bflo(r2.y) * w1reg[18] + bfhi(r2.y) * w1reg[19];
    o2 += bflo(r2.z) * w1reg[20] + bfhi(r2.z) * w1reg[21];
    o2 += bflo(r2.w) * w1reg[22] + bfhi(r2.w) * w1reg[23];
    o3 += bflo(r3.x) * w1reg[24] + bfhi(r3.x) * w1reg[25];
    o3 += bflo(r3.y) * w1reg[26] + bfhi(r3.y) * w1reg[27];
    o3 += bflo(r3.z) * w1reg[28] + bfhi(r3.z) * w1reg[29];
    o3 += bflo(r3.w) * w1reg[30] + bfhi(r3.w) * w1reg[31];
    float inv = 1.f / (den1[(size_t)gn * 8 + h] + 1e-16f);
    float r = ((o0 + o1) + (o2 + o3)) * inv + b1reg;
    sh1[n * PAD + tid] = r > 0.f ? r : 0.f;
  }
  __syncthreads();
  // P2: xs2 partials (k in h-range), float4 broadcast reads from sh1
  int wv = tid >> 6, lane = tid & 63;
  for (int n = 0; n < NB; ++n) {
    const float4* hp = (const float4*)&sh1[n * PAD + h * 32];
    float4 q0 = hp[0], q1 = hp[1], q2 = hp[2], q3 = hp[3];
    float4 q4 = hp[4], q5 = hp[5], q6 = hp[6], q7 = hp[7];
    float p0 = 0.f, p1 = 0.f, p2 = 0.f, p3 = 0.f;
    p0 += q0.x * w2reg[0] + q0.y * w2reg[1] + q0.z * w2reg[2] + q0.w * w2reg[3];
    p0 += q1.x * w2reg[4] + q1.y * w2reg[5] + q1.z * w2reg[6] + q1.w * w2reg[7];
    p1 += q2.x * w2reg[8] + q2.y * w2reg[9] + q2.z * w2reg[10] + q2.w * w2reg[11];
    p1 += q3.x * w2reg[12] + q3.y * w2reg[13] + q3.z * w2reg[14] + q3.w * w2reg[15];
    p2 += q4.x * w2reg[16] + q4.y * w2reg[17] + q4.z * w2reg[18] + q4.w * w2reg[19];
    p2 += q5.x * w2reg[20] + q5.y * w2reg[21] + q5.z * w2reg[22] + q5.w * w2reg[23];
    p3 += q6.x * w2reg[24] + q6.y * w2reg[25] + q6.z * w2reg[26] + q6.w * w2reg[27];
    p3 += q7.x * w2reg[28] + q7.y * w2reg[29] + q7.z * w2reg[30] + q7.w * w2reg[31];
    float pp = (p0 + p1) + (p2 + p3);
    pp += __shfl_xor(pp, 32);
    if (lane < 32) part[wv * (NB * 32) + n * 32 + c] = pp;
  }
  __syncthreads();
  // combine xs2 partials -> bf16 write (NB*32 = 512 slots, 2 per thread)
#pragma unroll
  for (int q = 0; q < 2; ++q) {
    int slot = tid + 256 * q;
    int nn = slot >> 5, cc = slot & 31;
    float s = part[slot] + part[512 + slot] + part[1024 + slot] +
              part[1536 + slot];
    float other = __shfl_xor(s, 1);
    int gn = n0 + nn;
    if (!(cc & 1)) xs2b[(size_t)gn * 16 + (cc >> 1)] = packbf(s, other);
  }
  // v2 dots: 16 threads per node (nn = tid>>4, kg = tid&15), k = kg+16q
  {
    int nn = tid >> 4, kg = tid & 15;
    const float* row = &sh1[nn * PAD];
    float ssum = 0.f, dsum = 0.f;
#pragma unroll
    for (int q = 0; q < 16; ++q) {
      int ki = kg + 16 * q;
      float hv = row[ki];
      ssum += hv * v2sl[ki];
      dsum += hv * v2dl[ki];
    }
    ssum += __shfl_xor(ssum, 1);
    dsum += __shfl_xor(dsum, 1);
    ssum += __shfl_xor(ssum, 2);
    dsum += __shfl_xor(dsum, 2);
    ssum += __shfl_xor(ssum, 4);
    dsum += __shfl_xor(dsum, 4);
    ssum += __shfl_xor(ssum, 8);
    dsum += __shfl_xor(dsum, 8);
    int gn = n0 + nn;
    if (kg == 0) {
      as2[gn] = ssum;
      ad2[gn] = dsum;
    }
  }
}

// ---------------------------------------------------------------------------
// conv2 aggregate: 8 nodes/block; xs2b 3.2MB L2-resident gather. h2 fp32.
// ---------------------------------------------------------------------------
__global__ __launch_bounds__(256) void k_agg2(
    const int* __restrict__ cnt, const int* __restrict__ csr,
    const u32* __restrict__ xs2b, const float* __restrict__ as2,
    const float* __restrict__ ad2, const float* __restrict__ b2,
    float* __restrict__ h2) {
  int tid = threadIdx.x;
  int n = blockIdx.x * 8 + (tid >> 5);
  int sub = tid & 31, g = sub >> 4, l = sub & 15;
  if (n >= NN) return;
  float adn = ad2[n];
  int m = min(cnt[n], CAP);
  const int* cs = csr + (size_t)n * CAP;
  float a0 = 0.f, a1v = 0.f, ea = 0.f;
  int j = g;
  for (; j + 2 < m; j += 4) {
    int sA = cs[j], sB = cs[j + 2];
    float alA = as2[sA] + adn; alA = alA > 0.f ? alA : 0.2f * alA;
    float alB = as2[sB] + adn; alB = alB > 0.f ? alB : 0.2f * alB;
    float eA = __expf(alA), eB = __expf(alB);
    u32 vA = xs2b[(size_t)sA * 16 + l], vB = xs2b[(size_t)sB * 16 + l];
    a0 += bflo(vA) * eA + bflo(vB) * eB;
    a1v += bfhi(vA) * eA + bfhi(vB) * eB;
    ea += eA + eB;
  }
  for (; j < m; j += 2) {
    int s = cs[j];
    float al = as2[s] + adn; al = al > 0.f ? al : 0.2f * al;
    float ee = __expf(al);
    u32 v = xs2b[(size_t)s * 16 + l];
    a0 += bflo(v) * ee;
    a1v += bfhi(v) * ee;
    ea += ee;
  }
  a0 += __shfl_xor(a0, 16);
  a1v += __shfl_xor(a1v, 16);
  ea += __shfl_xor(ea, 16);
  if (g == 0) {
    float inv = 1.f / (ea + 1e-16f);
    float o0 = a0 * inv + b2[2 * l];
    float o1 = a1v * inv + b2[2 * l + 1];
    ((float2*)h2)[(size_t)n * 16 + l] = make_float2(o0, o1);
  }
}

// ---------------------------------------------------------------------------
// classifier: 8 lanes per label, float4 loads, shfl reduce
// ---------------------------------------------------------------------------
__global__ __launch_bounds__(256) void k_pred(const int* __restrict__ eli,
                                              const float* __restrict__ h2,
                                              float* __restrict__ out) {
  int gid = blockIdx.x * 256 + threadIdx.x;
  int lab = gid >> 3, q = gid & 7;
  if (lab >= NL) return;
  int a = eli[lab], b = eli[NL + lab];
  float4 va = ((const float4*)(h2 + (size_t)a * HID))[q];
  float4 vb = ((const float4*)(h2 + (size_t)b * HID))[q];
  float s = va.x * vb.x + va.y * vb.y + va.z * vb.z + va.w * vb.w;
  s += __shfl_xor(s, 1);
  s += __shfl_xor(s, 2);
  s += __shfl_xor(s, 4);
  if (q == 0) out[lab] = s;
}

extern "C" void kernel_launch(void* const* d_in, const int* in_sizes, int n_in,
                              void* d_out, int out_size, void* d_ws, size_t ws_size,
                              hipStream_t stream) {
  const float* x     = (const float*)d_in[0];
  const int*   ei    = (const int*)d_in[1];
  const int*   eli   = (const int*)d_in[2];
  const float* lin_w = (const float*)d_in[3];
  const float* lin_b = (const float*)d_in[4];
  const float* w1s   = (const float*)d_in[5];
  const float* w1d   = (const float*)d_in[6];
  const float* a1s   = (const float*)d_in[7];
  const float* a1d   = (const float*)d_in[8];
  const float* b1    = (const float*)d_in[9];
  const float* w2s   = (const float*)d_in[10];
  const float* w2d   = (const float*)d_in[11];
  const float* a2s   = (const float*)d_in[12];
  const float* a2d   = (const float*)d_in[13];
  const float* b2    = (const float*)d_in[14];
  float* out = (float*)d_out;

  char* p = (char*)d_ws;
  auto take = [&](size_t bytes) {
    char* r = p;
    p += (bytes + 255) & ~(size_t)255;
    return r;
  };
  int*   cnt  = (int*)take((size_t)NN * 4);           // zeroed per call
  int*   csr  = (int*)take((size_t)NN * CAP * 4);     // 12.8MB
  u32*   h0b  = (u32*)take((size_t)NN * 16 * 4);      // 3.2MB (bf16 pairs)
  float* as1  = (float*)take((size_t)NN * 8 * 4);
  float* ad1  = (float*)take((size_t)NN * 8 * 4);
  u32*   aggb = (u32*)take((size_t)NN * 128 * 4);     // 25.6MB (bf16 pairs)
  float* den1 = (float*)take((size_t)NN * 8 * 4);     // 1.6MB
  u32*   xs2b = (u32*)take((size_t)NN * 16 * 4);      // 3.2MB
  float* as2  = (float*)take((size_t)NN * 4);
  float* ad2  = (float*)take((size_t)NN * 4);
  float* h2   = (float*)take((size_t)NN * HID * 4);   // fp32
  float* v1s  = (float*)take(256 * 4);
  float* v1d  = (float*)take(256 * 4);
  float* v2s  = (float*)take(256 * 4);
  float* v2d  = (float*)take(256 * 4);

  const int* esrc = ei;
  const int* edst = ei + NE;

  hipMemsetAsync(cnt, 0, (size_t)NN * 4, stream);
  k_vprep<<<1, 256, 0, stream>>>(w1s, w1d, a1s, a1d, w2s, w2d, a2s, a2d,
                                 v1s, v1d, v2s, v2d);
  k_fill<<<(NE + 255) / 256, 256, 0, stream>>>(esrc, edst, cnt, csr);
  k_l1<<<(NN + 31) / 32, 256, 0, stream>>>(x, lin_w, lin_b, v1s, v1d,
                                           h0b, as1, ad1);
  k_aggE<<<NN / 4, 256, 0, stream>>>(cnt, csr, h0b, as1, ad1, aggb, den1);
  k_p12<<<NN / NB, 256, 0, stream>>>(aggb, den1, w1s, b1, w2s,
                                     v2s, v2d, xs2b, as2, ad2);
  k_agg2<<<(NN + 7) / 8, 256, 0, stream>>>(cnt, csr, xs2b, as2, ad2, b2, h2);
  k_pred<<<(NL * 8 + 255) / 256, 256, 0, stream>>>(eli, h2, out);
}

// Round 12
// 273.062 us; speedup vs baseline: 1.1655x; 1.1512x over previous
//
#include <hip/hip_runtime.h>

#define NN 50000
#define NE 800000
#define NL 200000
#define FEAT 128
#define HID 32
#define HEADS 8
#define H1 256   // HEADS*HID
#define CAP 64   // per-node CSR bucket capacity (P(deg>64) ~ 1e-20 for Poisson(16))

using u32 = unsigned int;
typedef __attribute__((ext_vector_type(8))) short bf16x8;
typedef __attribute__((ext_vector_type(4))) float f32x4;
union U4B { uint4 u; bf16x8 v; };

__device__ __forceinline__ float bflo(u32 v) { return __uint_as_float(v << 16); }
__device__ __forceinline__ float bfhi(u32 v) { return __uint_as_float(v & 0xffff0000u); }
__device__ __forceinline__ u32 packbf(float a, float b) {
  u32 ua = __float_as_uint(a), ub = __float_as_uint(b);
  ua += 0x7fffu + ((ua >> 16) & 1u);   // RNE
  ub += 0x7fffu + ((ub >> 16) & 1u);
  return (ua >> 16) | (ub & 0xffff0000u);
}
__device__ __forceinline__ unsigned short bf16r(float f) {
  u32 u = __float_as_uint(f);
  u += 0x7fffu + ((u >> 16) & 1u);
  return (unsigned short)(u >> 16);
}

// ---------------------------------------------------------------------------
// v-vector precompute + weight pre-swizzle into MFMA B-fragment layout.
// B-frag convention (mfma_f32_16x16x32_bf16): lane l holds B[k0+b][j],
// b=0..7, k0=(l>>4)*8, j = l&15  (8 contiguous k per lane -> one uint4).
// w1sb[(h*2+nh)*64 + lane]; w2sb[(kc*2+nh)*64 + lane].
// ---------------------------------------------------------------------------
__global__ __launch_bounds__(256) void k_vprep(
    const float* __restrict__ w1s, const float* __restrict__ w1d,
    const float* __restrict__ a1s, const float* __restrict__ a1d,
    const float* __restrict__ w2s, const float* __restrict__ w2d,
    const float* __restrict__ a2s, const float* __restrict__ a2d,
    float* __restrict__ v1s, float* __restrict__ v1d,
    float* __restrict__ v2s, float* __restrict__ v2d,
    uint4* __restrict__ w1sb, uint4* __restrict__ w2sb) {
  int tid = threadIdx.x;
  int k = tid >> 3, h = tid & 7;
  float ss = 0.f, sd = 0.f;
  for (int c = 0; c < 32; ++c) {
    ss += w1s[k * H1 + h * 32 + c] * a1s[h * 32 + c];
    sd += w1d[k * H1 + h * 32 + c] * a1d[h * 32 + c];
  }
  v1s[k * 8 + h] = ss;
  v1d[k * 8 + h] = sd;
  float s2 = 0.f, d2 = 0.f;
  for (int c = 0; c < 32; ++c) {
    s2 += w2s[tid * 32 + c] * a2s[c];
    d2 += w2d[tid * 32 + c] * a2d[c];
  }
  v2s[tid] = s2;
  v2d[tid] = d2;
  // W1s frags: [8 heads][2 nh][64 lanes]
  for (int u = tid; u < 1024; u += 256) {
    int f = u >> 6, lane = u & 63;
    int hh = f >> 1, nh = f & 1;
    int k0 = (lane >> 4) * 8, j = hh * 32 + nh * 16 + (lane & 15);
    uint4 v;
    v.x = packbf(w1s[(k0 + 0) * H1 + j], w1s[(k0 + 1) * H1 + j]);
    v.y = packbf(w1s[(k0 + 2) * H1 + j], w1s[(k0 + 3) * H1 + j]);
    v.z = packbf(w1s[(k0 + 4) * H1 + j], w1s[(k0 + 5) * H1 + j]);
    v.w = packbf(w1s[(k0 + 6) * H1 + j], w1s[(k0 + 7) * H1 + j]);
    w1sb[u] = v;
  }
  // W2s frags: [8 kc][2 nh][64 lanes]
  for (int u = tid; u < 1024; u += 256) {
    int f = u >> 6, lane = u & 63;
    int kc = f >> 1, nh = f & 1;
    int k0 = kc * 32 + (lane >> 4) * 8, j = nh * 16 + (lane & 15);
    uint4 v;
    v.x = packbf(w2s[(k0 + 0) * HID + j], w2s[(k0 + 1) * HID + j]);
    v.y = packbf(w2s[(k0 + 2) * HID + j], w2s[(k0 + 3) * HID + j]);
    v.z = packbf(w2s[(k0 + 4) * HID + j], w2s[(k0 + 5) * HID + j]);
    v.w = packbf(w2s[(k0 + 6) * HID + j], w2s[(k0 + 7) * HID + j]);
    w2sb[u] = v;
  }
}

// ---------------------------------------------------------------------------
// Bucketed CSR fill
// ---------------------------------------------------------------------------
__global__ void k_fill(const int* __restrict__ src, const int* __restrict__ dst,
                       int* __restrict__ cnt, int* __restrict__ csr) {
  int e = blockIdx.x * 256 + threadIdx.x;
  if (e >= NE) return;
  int d = dst[e];
  int slot = atomicAdd(&cnt[d], 1);
  if (slot < CAP) csr[(size_t)d * CAP + slot] = src[e];
}

// ---------------------------------------------------------------------------
// Layer-1 prep: h0 = x@lin_w+lin_b (LDS), write h0b (bf16, 3.2MB) + as1/ad1.
// ---------------------------------------------------------------------------
__global__ __launch_bounds__(256) void k_l1(
    const float* __restrict__ x, const float* __restrict__ lin_w,
    const float* __restrict__ lin_b, const float* __restrict__ v1s,
    const float* __restrict__ v1d, u32* __restrict__ h0b,
    float* __restrict__ as1, float* __restrict__ ad1) {
  __shared__ float wl[FEAT * HID];   // 16KB
  __shared__ float xl[32 * FEAT];    // 16KB
  __shared__ float h0l[32 * HID];    // 4KB
  __shared__ float vsl[HID * 8], vdl[HID * 8], bl[HID];
  int tid = threadIdx.x;
  for (int i = tid; i < (FEAT * HID) / 4; i += 256)
    ((float4*)wl)[i] = ((const float4*)lin_w)[i];
  vsl[tid] = v1s[tid];
  vdl[tid] = v1d[tid];
  if (tid < HID) bl[tid] = lin_b[tid];
  int n0 = blockIdx.x * 32;
  for (int i = tid; i < (32 * FEAT) / 4; i += 256) {
    int n = n0 + (i >> 5);
    ((float4*)xl)[i] = (n < NN) ? ((const float4*)x)[(size_t)n * 32 + (i & 31)]
                                : make_float4(0.f, 0.f, 0.f, 0.f);
  }
  __syncthreads();
  {
    int nl = tid >> 5, c = tid & 31;
    float acc[4] = {0.f, 0.f, 0.f, 0.f};
    for (int k = 0; k < FEAT; ++k) {
      float wv = wl[k * HID + c];
#pragma unroll
      for (int j = 0; j < 4; ++j) acc[j] += xl[(nl + 8 * j) * FEAT + k] * wv;
    }
#pragma unroll
    for (int j = 0; j < 4; ++j) h0l[(nl + 8 * j) * HID + c] = acc[j] + bl[c];
  }
  __syncthreads();
  for (int i = tid; i < 512; i += 256) {
    int nl = i >> 4, cp = i & 15;
    int n = n0 + nl;
    if (n < NN)
      h0b[(size_t)n * 16 + cp] =
          packbf(h0l[nl * 32 + 2 * cp], h0l[nl * 32 + 2 * cp + 1]);
  }
  {
    int nl = tid >> 3, h = tid & 7;
    int n = n0 + nl;
    if (n < NN) {
      float ss = 0.f, sd = 0.f;
#pragma unroll
      for (int k = 0; k < HID; ++k) {
        float hv = h0l[nl * HID + k];
        ss += hv * vsl[k * 8 + h];
        sd += hv * vdl[k * 8 + h];
      }
      as1[(size_t)n * 8 + h] = ss;
      ad1[(size_t)n * 8 + h] = sd;
    }
  }
}

// ---------------------------------------------------------------------------
// Edge aggregation in h0-space. Wave per node, no LDS, no cross-lane ops in
// the loop. Lane = (head h = lane>>3, col-quarter cq = lane&7).
// ---------------------------------------------------------------------------
__global__ __launch_bounds__(256) void k_aggE(
    const int* __restrict__ cnt, const int* __restrict__ csr,
    const u32* __restrict__ h0b, const float* __restrict__ as1,
    const float* __restrict__ ad1, u32* __restrict__ aggb,
    float* __restrict__ den1) {
  int tid = threadIdx.x;
  int w = tid >> 6, lane = tid & 63;
  int h = lane >> 3, cq = lane & 7;
  int n = blockIdx.x * 4 + w;          // grid = NN/4 exactly
  const uint2* h0b2 = (const uint2*)h0b;
  float adreg = ad1[(size_t)n * 8 + h];
  float a0 = 0.f, a1 = 0.f, a2 = 0.f, a3 = 0.f, den = 0.f;
  int m = min(cnt[n], CAP);
  const int* cs = csr + (size_t)n * CAP;
  int j = 0;
  for (; j + 1 < m; j += 2) {
    int sA = cs[j], sB = cs[j + 1];
    float aA = as1[(size_t)sA * 8 + h] + adreg;
    aA = aA > 0.f ? aA : 0.2f * aA;
    float aB = as1[(size_t)sB * 8 + h] + adreg;
    aB = aB > 0.f ? aB : 0.2f * aB;
    float eA = __expf(aA), eB = __expf(aB);
    uint2 wA = h0b2[(size_t)sA * 8 + cq];
    uint2 wB = h0b2[(size_t)sB * 8 + cq];
    den += eA + eB;
    a0 += eA * bflo(wA.x) + eB * bflo(wB.x);
    a1 += eA * bfhi(wA.x) + eB * bfhi(wB.x);
    a2 += eA * bflo(wA.y) + eB * bflo(wB.y);
    a3 += eA * bfhi(wA.y) + eB * bfhi(wB.y);
  }
  if (j < m) {
    int sA = cs[j];
    float aA = as1[(size_t)sA * 8 + h] + adreg;
    aA = aA > 0.f ? aA : 0.2f * aA;
    float eA = __expf(aA);
    uint2 wA = h0b2[(size_t)sA * 8 + cq];
    den += eA;
    a0 += eA * bflo(wA.x);
    a1 += eA * bfhi(wA.x);
    a2 += eA * bflo(wA.y);
    a3 += eA * bfhi(wA.y);
  }
  if (cq == 0) den1[(size_t)n * 8 + h] = den;
  ((uint2*)aggb)[(size_t)n * 64 + h * 8 + cq] =
      make_uint2(packbf(a0, a1), packbf(a2, a3));
}

// ---------------------------------------------------------------------------
// P1+P2 projections via MFMA. Wave = 16 nodes (M=16); block = 4 waves = 64
// nodes; grid = ceil(NN/64). Per wave:
//  P1: per head h: D[16n x 32c] = A(agg, bf16) @ B(w1sb) -> 2 mfma; epilogue
//      h1 = relu(D*inv_den + b1) -> per-wave LDS tile (bf16, XOR-swizzled).
//  P2: D2[16n x 32c] = h1 @ W2s: 8 k-chunks x 2 nh, A-frags = swizzled b128
//      LDS reads; epilogue packs xs2b pairs via shfl.
//  as2/ad2: 4 lanes per node scalar dots from the LDS tile.
// No block barriers in the node path (per-wave LDS region).
// ---------------------------------------------------------------------------
__global__ __launch_bounds__(256) void k_p12(
    const u32* __restrict__ aggb, const float* __restrict__ den1,
    const uint4* __restrict__ w1sb, const uint4* __restrict__ w2sb,
    const float* __restrict__ b1, const float* __restrict__ v2s,
    const float* __restrict__ v2d, u32* __restrict__ xs2b,
    float* __restrict__ as2, float* __restrict__ ad2) {
  __shared__ unsigned short h1l[4][16 * 256];  // 8KB per wave
  __shared__ float v2sl[H1], v2dl[H1];
  int tid = threadIdx.x;
  v2sl[tid] = v2s[tid];
  v2dl[tid] = v2d[tid];
  __syncthreads();
  int w = tid >> 6, lane = tid & 63;
  int gn0 = blockIdx.x * 64 + w * 16;
  if (gn0 < NN) {   // whole-wave granular (NN = 781*64 + 16)
    int lrow = lane & 15, lq = lane >> 4;
    unsigned short* myh1 = h1l[w];
    // ---- P1 ----
    const uint4* aggv = (const uint4*)aggb;   // 32 uint4 per node
    int gn_a = gn0 + lrow;
    U4B afrag[8];
#pragma unroll
    for (int h = 0; h < 8; ++h)
      afrag[h].u = aggv[(size_t)gn_a * 32 + h * 4 + lq];
#pragma unroll
    for (int h = 0; h < 8; ++h) {
      float inv[4];
#pragma unroll
      for (int r = 0; r < 4; ++r)
        inv[r] = 1.f / (den1[(size_t)(gn0 + lq * 4 + r) * 8 + h] + 1e-16f);
#pragma unroll
      for (int nh = 0; nh < 2; ++nh) {
        U4B bfrag;
        bfrag.u = ((const uint4*)w1sb)[(h * 2 + nh) * 64 + lane];
        f32x4 dz = {0.f, 0.f, 0.f, 0.f};
        f32x4 d = __builtin_amdgcn_mfma_f32_16x16x32_bf16(afrag[h].v, bfrag.v,
                                                          dz, 0, 0, 0);
        int col = h * 32 + nh * 16 + lrow;
        float bb = b1[col];
#pragma unroll
        for (int r = 0; r < 4; ++r) {
          float hv = d[r] * inv[r] + bb;
          hv = hv > 0.f ? hv : 0.f;
          int node = lq * 4 + r;
          int byt = (node * 512 + col * 2) ^ ((node & 7) << 4);
          *(unsigned short*)((char*)myh1 + byt) = bf16r(hv);
        }
      }
    }
    // ---- P2 ----
    f32x4 d20 = {0.f, 0.f, 0.f, 0.f}, d21 = {0.f, 0.f, 0.f, 0.f};
#pragma unroll
    for (int kc = 0; kc < 8; ++kc) {
      int byt = (lrow * 512 + (kc * 32 + lq * 8) * 2) ^ ((lrow & 7) << 4);
      U4B a2;
      a2.u = *(const uint4*)((const char*)myh1 + byt);
      U4B b20, b21;
      b20.u = ((const uint4*)w2sb)[(kc * 2 + 0) * 64 + lane];
      b21.u = ((const uint4*)w2sb)[(kc * 2 + 1) * 64 + lane];
      d20 = __builtin_amdgcn_mfma_f32_16x16x32_bf16(a2.v, b20.v, d20, 0, 0, 0);
      d21 = __builtin_amdgcn_mfma_f32_16x16x32_bf16(a2.v, b21.v, d21, 0, 0, 0);
    }
#pragma unroll
    for (int r = 0; r < 4; ++r) {
      int gn = gn0 + lq * 4 + r;
      float s0 = d20[r], s1 = d21[r];
      float o0 = __shfl_xor(s0, 1), o1 = __shfl_xor(s1, 1);
      if (!(lane & 1)) {
        xs2b[(size_t)gn * 16 + (lrow >> 1)] = packbf(s0, o0);
        xs2b[(size_t)gn * 16 + 8 + (lrow >> 1)] = packbf(s1, o1);
      }
    }
    // ---- as2/ad2: lane = (node = lane>>2, kq = lane&3) ----
    {
      int node8 = lane >> 2, kq = lane & 3;
      float ssum = 0.f, dsum = 0.f;
#pragma unroll
      for (int t = 0; t < 32; ++t) {
        int pi = kq * 32 + t;   // u32 pair index: cols 2pi, 2pi+1
        int byt = (node8 * 512 + pi * 4) ^ ((node8 & 7) << 4);
        u32 vv = *(const u32*)((const char*)myh1 + byt);
        float lo = bflo(vv), hi = bfhi(vv);
        ssum += lo * v2sl[2 * pi] + hi * v2sl[2 * pi + 1];
        dsum += lo * v2dl[2 * pi] + hi * v2dl[2 * pi + 1];
      }
      ssum += __shfl_xor(ssum, 1);
      dsum += __shfl_xor(dsum, 1);
      ssum += __shfl_xor(ssum, 2);
      dsum += __shfl_xor(dsum, 2);
      if (kq == 0) {
        as2[gn0 + node8] = ssum;
        ad2[gn0 + node8] = dsum;
      }
    }
  }
}

// ---------------------------------------------------------------------------
// conv2 aggregate: 8 nodes/block; xs2b 3.2MB L2-resident gather. h2 fp32.
// ---------------------------------------------------------------------------
__global__ __launch_bounds__(256) void k_agg2(
    const int* __restrict__ cnt, const int* __restrict__ csr,
    const u32* __restrict__ xs2b, const float* __restrict__ as2,
    const float* __restrict__ ad2, const float* __restrict__ b2,
    float* __restrict__ h2) {
  int tid = threadIdx.x;
  int n = blockIdx.x * 8 + (tid >> 5);
  int sub = tid & 31, g = sub >> 4, l = sub & 15;
  if (n >= NN) return;
  float adn = ad2[n];
  int m = min(cnt[n], CAP);
  const int* cs = csr + (size_t)n * CAP;
  float a0 = 0.f, a1v = 0.f, ea = 0.f;
  int j = g;
  for (; j + 2 < m; j += 4) {
    int sA = cs[j], sB = cs[j + 2];
    float alA = as2[sA] + adn; alA = alA > 0.f ? alA : 0.2f * alA;
    float alB = as2[sB] + adn; alB = alB > 0.f ? alB : 0.2f * alB;
    float eA = __expf(alA), eB = __expf(alB);
    u32 vA = xs2b[(size_t)sA * 16 + l], vB = xs2b[(size_t)sB * 16 + l];
    a0 += bflo(vA) * eA + bflo(vB) * eB;
    a1v += bfhi(vA) * eA + bfhi(vB) * eB;
    ea += eA + eB;
  }
  for (; j < m; j += 2) {
    int s = cs[j];
    float al = as2[s] + adn; al = al > 0.f ? al : 0.2f * al;
    float ee = __expf(al);
    u32 v = xs2b[(size_t)s * 16 + l];
    a0 += bflo(v) * ee;
    a1v += bfhi(v) * ee;
    ea += ee;
  }
  a0 += __shfl_xor(a0, 16);
  a1v += __shfl_xor(a1v, 16);
  ea += __shfl_xor(ea, 16);
  if (g == 0) {
    float inv = 1.f / (ea + 1e-16f);
    float o0 = a0 * inv + b2[2 * l];
    float o1 = a1v * inv + b2[2 * l + 1];
    ((float2*)h2)[(size_t)n * 16 + l] = make_float2(o0, o1);
  }
}

// ---------------------------------------------------------------------------
// classifier: 8 lanes per label, float4 loads, shfl reduce
// ---------------------------------------------------------------------------
__global__ __launch_bounds__(256) void k_pred(const int* __restrict__ eli,
                                              const float* __restrict__ h2,
                                              float* __restrict__ out) {
  int gid = blockIdx.x * 256 + threadIdx.x;
  int lab = gid >> 3, q = gid & 7;
  if (lab >= NL) return;
  int a = eli[lab], b = eli[NL + lab];
  float4 va = ((const float4*)(h2 + (size_t)a * HID))[q];
  float4 vb = ((const float4*)(h2 + (size_t)b * HID))[q];
  float s = va.x * vb.x + va.y * vb.y + va.z * vb.z + va.w * vb.w;
  s += __shfl_xor(s, 1);
  s += __shfl_xor(s, 2);
  s += __shfl_xor(s, 4);
  if (q == 0) out[lab] = s;
}

extern "C" void kernel_launch(void* const* d_in, const int* in_sizes, int n_in,
                              void* d_out, int out_size, void* d_ws, size_t ws_size,
                              hipStream_t stream) {
  const float* x     = (const float*)d_in[0];
  const int*   ei    = (const int*)d_in[1];
  const int*   eli   = (const int*)d_in[2];
  const float* lin_w = (const float*)d_in[3];
  const float* lin_b = (const float*)d_in[4];
  const float* w1s   = (const float*)d_in[5];
  const float* w1d   = (const float*)d_in[6];
  const float* a1s   = (const float*)d_in[7];
  const float* a1d   = (const float*)d_in[8];
  const float* b1    = (const float*)d_in[9];
  const float* w2s   = (const float*)d_in[10];
  const float* w2d   = (const float*)d_in[11];
  const float* a2s   = (const float*)d_in[12];
  const float* a2d   = (const float*)d_in[13];
  const float* b2    = (const float*)d_in[14];
  float* out = (float*)d_out;

  char* p = (char*)d_ws;
  auto take = [&](size_t bytes) {
    char* r = p;
    p += (bytes + 255) & ~(size_t)255;
    return r;
  };
  int*   cnt  = (int*)take((size_t)NN * 4);           // zeroed per call
  int*   csr  = (int*)take((size_t)NN * CAP * 4);     // 12.8MB
  u32*   h0b  = (u32*)take((size_t)NN * 16 * 4);      // 3.2MB (bf16 pairs)
  float* as1  = (float*)take((size_t)NN * 8 * 4);
  float* ad1  = (float*)take((size_t)NN * 8 * 4);
  u32*   aggb = (u32*)take((size_t)NN * 128 * 4);     // 25.6MB (bf16 pairs)
  float* den1 = (float*)take((size_t)NN * 8 * 4);     // 1.6MB
  u32*   xs2b = (u32*)take((size_t)NN * 16 * 4);      // 3.2MB
  float* as2  = (float*)take((size_t)NN * 4);
  float* ad2  = (float*)take((size_t)NN * 4);
  float* h2   = (float*)take((size_t)NN * HID * 4);   // fp32
  float* v1s  = (float*)take(256 * 4);
  float* v1d  = (float*)take(256 * 4);
  float* v2s  = (float*)take(256 * 4);
  float* v2d  = (float*)take(256 * 4);
  uint4* w1sb = (uint4*)take(1024 * 16);              // 16KB B-frags
  uint4* w2sb = (uint4*)take(1024 * 16);              // 16KB B-frags

  const int* esrc = ei;
  const int* edst = ei + NE;

  hipMemsetAsync(cnt, 0, (size_t)NN * 4, stream);
  k_vprep<<<1, 256, 0, stream>>>(w1s, w1d, a1s, a1d, w2s, w2d, a2s, a2d,
                                 v1s, v1d, v2s, v2d, w1sb, w2sb);
  k_fill<<<(NE + 255) / 256, 256, 0, stream>>>(esrc, edst, cnt, csr);
  k_l1<<<(NN + 31) / 32, 256, 0, stream>>>(x, lin_w, lin_b, v1s, v1d,
                                           h0b, as1, ad1);
  k_aggE<<<NN / 4, 256, 0, stream>>>(cnt, csr, h0b, as1, ad1, aggb, den1);
  k_p12<<<(NN + 63) / 64, 256, 0, stream>>>(aggb, den1, w1sb, w2sb, b1,
                                            v2s, v2d, xs2b, as2, ad2);
  k_agg2<<<(NN + 7) / 8, 256, 0, stream>>>(cnt, csr, xs2b, as2, ad2, b2, h2);
  k_pred<<<(NL * 8 + 255) / 256, 256, 0, stream>>>(eli, h2, out);
}

// Round 13
// 261.497 us; speedup vs baseline: 1.2171x; 1.0442x over previous
//
#include <hip/hip_runtime.h>

#define NN 50000
#define NE 800000
#define NL 200000
#define FEAT 128
#define HID 32
#define HEADS 8
#define H1 256   // HEADS*HID
#define CAP 64   // per-node CSR bucket capacity (P(deg>64) ~ 1e-20 for Poisson(16))

using u32 = unsigned int;
typedef __attribute__((ext_vector_type(8))) short bf16x8;
typedef __attribute__((ext_vector_type(4))) float f32x4;
union U4B { uint4 u; bf16x8 v; };

__device__ __forceinline__ float bflo(u32 v) { return __uint_as_float(v << 16); }
__device__ __forceinline__ float bfhi(u32 v) { return __uint_as_float(v & 0xffff0000u); }
__device__ __forceinline__ u32 packbf(float a, float b) {
  u32 ua = __float_as_uint(a), ub = __float_as_uint(b);
  ua += 0x7fffu + ((ua >> 16) & 1u);   // RNE
  ub += 0x7fffu + ((ub >> 16) & 1u);
  return (ua >> 16) | (ub & 0xffff0000u);
}
__device__ __forceinline__ unsigned short bf16r(float f) {
  u32 u = __float_as_uint(f);
  u += 0x7fffu + ((u >> 16) & 1u);
  return (unsigned short)(u >> 16);
}

// ---------------------------------------------------------------------------
// v-vector precompute + weight pre-swizzle into MFMA B-fragment layout.
// ---------------------------------------------------------------------------
__global__ __launch_bounds__(256) void k_vprep(
    const float* __restrict__ w1s, const float* __restrict__ w1d,
    const float* __restrict__ a1s, const float* __restrict__ a1d,
    const float* __restrict__ w2s, const float* __restrict__ w2d,
    const float* __restrict__ a2s, const float* __restrict__ a2d,
    float* __restrict__ v1s, float* __restrict__ v1d,
    float* __restrict__ v2s, float* __restrict__ v2d,
    uint4* __restrict__ w1sb, uint4* __restrict__ w2sb) {
  int tid = threadIdx.x;
  int k = tid >> 3, h = tid & 7;
  float ss = 0.f, sd = 0.f;
  for (int c = 0; c < 32; ++c) {
    ss += w1s[k * H1 + h * 32 + c] * a1s[h * 32 + c];
    sd += w1d[k * H1 + h * 32 + c] * a1d[h * 32 + c];
  }
  v1s[k * 8 + h] = ss;
  v1d[k * 8 + h] = sd;
  float s2 = 0.f, d2 = 0.f;
  for (int c = 0; c < 32; ++c) {
    s2 += w2s[tid * 32 + c] * a2s[c];
    d2 += w2d[tid * 32 + c] * a2d[c];
  }
  v2s[tid] = s2;
  v2d[tid] = d2;
  // W1s frags: [8 heads][2 nh][64 lanes]
  for (int u = tid; u < 1024; u += 256) {
    int f = u >> 6, lane = u & 63;
    int hh = f >> 1, nh = f & 1;
    int k0 = (lane >> 4) * 8, j = hh * 32 + nh * 16 + (lane & 15);
    uint4 v;
    v.x = packbf(w1s[(k0 + 0) * H1 + j], w1s[(k0 + 1) * H1 + j]);
    v.y = packbf(w1s[(k0 + 2) * H1 + j], w1s[(k0 + 3) * H1 + j]);
    v.z = packbf(w1s[(k0 + 4) * H1 + j], w1s[(k0 + 5) * H1 + j]);
    v.w = packbf(w1s[(k0 + 6) * H1 + j], w1s[(k0 + 7) * H1 + j]);
    w1sb[u] = v;
  }
  // W2s frags: [8 kc][2 nh][64 lanes]
  for (int u = tid; u < 1024; u += 256) {
    int f = u >> 6, lane = u & 63;
    int kc = f >> 1, nh = f & 1;
    int k0 = kc * 32 + (lane >> 4) * 8, j = nh * 16 + (lane & 15);
    uint4 v;
    v.x = packbf(w2s[(k0 + 0) * HID + j], w2s[(k0 + 1) * HID + j]);
    v.y = packbf(w2s[(k0 + 2) * HID + j], w2s[(k0 + 3) * HID + j]);
    v.z = packbf(w2s[(k0 + 4) * HID + j], w2s[(k0 + 5) * HID + j]);
    v.w = packbf(w2s[(k0 + 6) * HID + j], w2s[(k0 + 7) * HID + j]);
    w2sb[u] = v;
  }
}

// ---------------------------------------------------------------------------
// Bucketed CSR fill
// ---------------------------------------------------------------------------
__global__ void k_fill(const int* __restrict__ src, const int* __restrict__ dst,
                       int* __restrict__ cnt, int* __restrict__ csr) {
  int e = blockIdx.x * 256 + threadIdx.x;
  if (e >= NE) return;
  int d = dst[e];
  int slot = atomicAdd(&cnt[d], 1);
  if (slot < CAP) csr[(size_t)d * CAP + slot] = src[e];
}

// ---------------------------------------------------------------------------
// Layer-1 prep: h0 = x@lin_w+lin_b (LDS), write h0b (bf16, 3.2MB) + as1/ad1.
// ---------------------------------------------------------------------------
__global__ __launch_bounds__(256) void k_l1(
    const float* __restrict__ x, const float* __restrict__ lin_w,
    const float* __restrict__ lin_b, const float* __restrict__ v1s,
    const float* __restrict__ v1d, u32* __restrict__ h0b,
    float* __restrict__ as1, float* __restrict__ ad1) {
  __shared__ float wl[FEAT * HID];   // 16KB
  __shared__ float xl[32 * FEAT];    // 16KB
  __shared__ float h0l[32 * HID];    // 4KB
  __shared__ float vsl[HID * 8], vdl[HID * 8], bl[HID];
  int tid = threadIdx.x;
  for (int i = tid; i < (FEAT * HID) / 4; i += 256)
    ((float4*)wl)[i] = ((const float4*)lin_w)[i];
  vsl[tid] = v1s[tid];
  vdl[tid] = v1d[tid];
  if (tid < HID) bl[tid] = lin_b[tid];
  int n0 = blockIdx.x * 32;
  for (int i = tid; i < (32 * FEAT) / 4; i += 256) {
    int n = n0 + (i >> 5);
    ((float4*)xl)[i] = (n < NN) ? ((const float4*)x)[(size_t)n * 32 + (i & 31)]
                                : make_float4(0.f, 0.f, 0.f, 0.f);
  }
  __syncthreads();
  {
    int nl = tid >> 5, c = tid & 31;
    float acc[4] = {0.f, 0.f, 0.f, 0.f};
    for (int k = 0; k < FEAT; ++k) {
      float wv = wl[k * HID + c];
#pragma unroll
      for (int j = 0; j < 4; ++j) acc[j] += xl[(nl + 8 * j) * FEAT + k] * wv;
    }
#pragma unroll
    for (int j = 0; j < 4; ++j) h0l[(nl + 8 * j) * HID + c] = acc[j] + bl[c];
  }
  __syncthreads();
  for (int i = tid; i < 512; i += 256) {
    int nl = i >> 4, cp = i & 15;
    int n = n0 + nl;
    if (n < NN)
      h0b[(size_t)n * 16 + cp] =
          packbf(h0l[nl * 32 + 2 * cp], h0l[nl * 32 + 2 * cp + 1]);
  }
  {
    int nl = tid >> 3, h = tid & 7;
    int n = n0 + nl;
    if (n < NN) {
      float ss = 0.f, sd = 0.f;
#pragma unroll
      for (int k = 0; k < HID; ++k) {
        float hv = h0l[nl * HID + k];
        ss += hv * vsl[k * 8 + h];
        sd += hv * vdl[k * 8 + h];
      }
      as1[(size_t)n * 8 + h] = ss;
      ad1[(size_t)n * 8 + h] = sd;
    }
  }
}

// ---------------------------------------------------------------------------
// Edge aggregation in h0-space. Wave per node, no LDS, no cross-lane ops.
// Lane = (head h = lane>>3, col-quarter cq = lane&7). 4-deep load pipeline:
// one int4 index load, then 4 independent as1+h0b chains in flight.
// ---------------------------------------------------------------------------
__global__ __launch_bounds__(256) void k_aggE(
    const int* __restrict__ cnt, const int* __restrict__ csr,
    const u32* __restrict__ h0b, const float* __restrict__ as1,
    const float* __restrict__ ad1, u32* __restrict__ aggb,
    float* __restrict__ den1) {
  int tid = threadIdx.x;
  int w = tid >> 6, lane = tid & 63;
  int h = lane >> 3, cq = lane & 7;
  int n = blockIdx.x * 4 + w;          // grid = NN/4 exactly
  const uint2* h0b2 = (const uint2*)h0b;
  float adreg = ad1[(size_t)n * 8 + h];
  float a0 = 0.f, a1 = 0.f, a2 = 0.f, a3 = 0.f, den = 0.f;
  int m = min(cnt[n], CAP);
  const int* cs = csr + (size_t)n * CAP;  // 256B-aligned
  int j = 0;
  for (; j + 3 < m; j += 4) {            // j%4==0 -> cs+j is 16B-aligned
    int4 s4 = *(const int4*)(cs + j);
    float x0 = as1[(size_t)s4.x * 8 + h] + adreg;
    float x1 = as1[(size_t)s4.y * 8 + h] + adreg;
    float x2 = as1[(size_t)s4.z * 8 + h] + adreg;
    float x3 = as1[(size_t)s4.w * 8 + h] + adreg;
    uint2 g0 = h0b2[(size_t)s4.x * 8 + cq];
    uint2 g1 = h0b2[(size_t)s4.y * 8 + cq];
    uint2 g2 = h0b2[(size_t)s4.z * 8 + cq];
    uint2 g3 = h0b2[(size_t)s4.w * 8 + cq];
    x0 = x0 > 0.f ? x0 : 0.2f * x0;
    x1 = x1 > 0.f ? x1 : 0.2f * x1;
    x2 = x2 > 0.f ? x2 : 0.2f * x2;
    x3 = x3 > 0.f ? x3 : 0.2f * x3;
    float e0 = __expf(x0), e1 = __expf(x1), e2 = __expf(x2), e3 = __expf(x3);
    den += (e0 + e1) + (e2 + e3);
    a0 += e0 * bflo(g0.x) + e1 * bflo(g1.x) + e2 * bflo(g2.x) + e3 * bflo(g3.x);
    a1 += e0 * bfhi(g0.x) + e1 * bfhi(g1.x) + e2 * bfhi(g2.x) + e3 * bfhi(g3.x);
    a2 += e0 * bflo(g0.y) + e1 * bflo(g1.y) + e2 * bflo(g2.y) + e3 * bflo(g3.y);
    a3 += e0 * bfhi(g0.y) + e1 * bfhi(g1.y) + e2 * bfhi(g2.y) + e3 * bfhi(g3.y);
  }
  for (; j < m; ++j) {
    int sA = cs[j];
    float aA = as1[(size_t)sA * 8 + h] + adreg;
    aA = aA > 0.f ? aA : 0.2f * aA;
    float eA = __expf(aA);
    uint2 gA = h0b2[(size_t)sA * 8 + cq];
    den += eA;
    a0 += eA * bflo(gA.x);
    a1 += eA * bfhi(gA.x);
    a2 += eA * bflo(gA.y);
    a3 += eA * bfhi(gA.y);
  }
  if (cq == 0) den1[(size_t)n * 8 + h] = den;
  ((uint2*)aggb)[(size_t)n * 64 + h * 8 + cq] =
      make_uint2(packbf(a0, a1), packbf(a2, a3));
}

// ---------------------------------------------------------------------------
// P1+P2 projections via MFMA (unchanged from round 12; dropped out of top-5).
// ---------------------------------------------------------------------------
__global__ __launch_bounds__(256) void k_p12(
    const u32* __restrict__ aggb, const float* __restrict__ den1,
    const uint4* __restrict__ w1sb, const uint4* __restrict__ w2sb,
    const float* __restrict__ b1, const float* __restrict__ v2s,
    const float* __restrict__ v2d, u32* __restrict__ xs2b,
    float* __restrict__ as2, float* __restrict__ ad2) {
  __shared__ unsigned short h1l[4][16 * 256];  // 8KB per wave
  __shared__ float v2sl[H1], v2dl[H1];
  int tid = threadIdx.x;
  v2sl[tid] = v2s[tid];
  v2dl[tid] = v2d[tid];
  __syncthreads();
  int w = tid >> 6, lane = tid & 63;
  int gn0 = blockIdx.x * 64 + w * 16;
  if (gn0 < NN) {   // whole-wave granular (NN = 781*64 + 16)
    int lrow = lane & 15, lq = lane >> 4;
    unsigned short* myh1 = h1l[w];
    // ---- P1 ----
    const uint4* aggv = (const uint4*)aggb;   // 32 uint4 per node
    int gn_a = gn0 + lrow;
    U4B afrag[8];
#pragma unroll
    for (int h = 0; h < 8; ++h)
      afrag[h].u = aggv[(size_t)gn_a * 32 + h * 4 + lq];
#pragma unroll
    for (int h = 0; h < 8; ++h) {
      float inv[4];
#pragma unroll
      for (int r = 0; r < 4; ++r)
        inv[r] = 1.f / (den1[(size_t)(gn0 + lq * 4 + r) * 8 + h] + 1e-16f);
#pragma unroll
      for (int nh = 0; nh < 2; ++nh) {
        U4B bfrag;
        bfrag.u = ((const uint4*)w1sb)[(h * 2 + nh) * 64 + lane];
        f32x4 dz = {0.f, 0.f, 0.f, 0.f};
        f32x4 d = __builtin_amdgcn_mfma_f32_16x16x32_bf16(afrag[h].v, bfrag.v,
                                                          dz, 0, 0, 0);
        int col = h * 32 + nh * 16 + lrow;
        float bb = b1[col];
#pragma unroll
        for (int r = 0; r < 4; ++r) {
          float hv = d[r] * inv[r] + bb;
          hv = hv > 0.f ? hv : 0.f;
          int node = lq * 4 + r;
          int byt = (node * 512 + col * 2) ^ ((node & 7) << 4);
          *(unsigned short*)((char*)myh1 + byt) = bf16r(hv);
        }
      }
    }
    // ---- P2 ----
    f32x4 d20 = {0.f, 0.f, 0.f, 0.f}, d21 = {0.f, 0.f, 0.f, 0.f};
#pragma unroll
    for (int kc = 0; kc < 8; ++kc) {
      int byt = (lrow * 512 + (kc * 32 + lq * 8) * 2) ^ ((lrow & 7) << 4);
      U4B a2;
      a2.u = *(const uint4*)((const char*)myh1 + byt);
      U4B b20, b21;
      b20.u = ((const uint4*)w2sb)[(kc * 2 + 0) * 64 + lane];
      b21.u = ((const uint4*)w2sb)[(kc * 2 + 1) * 64 + lane];
      d20 = __builtin_amdgcn_mfma_f32_16x16x32_bf16(a2.v, b20.v, d20, 0, 0, 0);
      d21 = __builtin_amdgcn_mfma_f32_16x16x32_bf16(a2.v, b21.v, d21, 0, 0, 0);
    }
#pragma unroll
    for (int r = 0; r < 4; ++r) {
      int gn = gn0 + lq * 4 + r;
      float s0 = d20[r], s1 = d21[r];
      float o0 = __shfl_xor(s0, 1), o1 = __shfl_xor(s1, 1);
      if (!(lane & 1)) {
        xs2b[(size_t)gn * 16 + (lrow >> 1)] = packbf(s0, o0);
        xs2b[(size_t)gn * 16 + 8 + (lrow >> 1)] = packbf(s1, o1);
      }
    }
    // ---- as2/ad2: lane = (node = lane>>2, kq = lane&3) ----
    {
      int node8 = lane >> 2, kq = lane & 3;
      float ssum = 0.f, dsum = 0.f;
#pragma unroll
      for (int t = 0; t < 32; ++t) {
        int pi = kq * 32 + t;   // u32 pair index: cols 2pi, 2pi+1
        int byt = (node8 * 512 + pi * 4) ^ ((node8 & 7) << 4);
        u32 vv = *(const u32*)((const char*)myh1 + byt);
        float lo = bflo(vv), hi = bfhi(vv);
        ssum += lo * v2sl[2 * pi] + hi * v2sl[2 * pi + 1];
        dsum += lo * v2dl[2 * pi] + hi * v2dl[2 * pi + 1];
      }
      ssum += __shfl_xor(ssum, 1);
      dsum += __shfl_xor(dsum, 1);
      ssum += __shfl_xor(ssum, 2);
      dsum += __shfl_xor(dsum, 2);
      if (kq == 0) {
        as2[gn0 + node8] = ssum;
        ad2[gn0 + node8] = dsum;
      }
    }
  }
}

// ---------------------------------------------------------------------------
// conv2 aggregate: 8 nodes/block, 2 edge groups x 16 lanes; 4-deep pipeline
// per group (8 edges in flight per node).
// ---------------------------------------------------------------------------
__global__ __launch_bounds__(256) void k_agg2(
    const int* __restrict__ cnt, const int* __restrict__ csr,
    const u32* __restrict__ xs2b, const float* __restrict__ as2,
    const float* __restrict__ ad2, const float* __restrict__ b2,
    float* __restrict__ h2) {
  int tid = threadIdx.x;
  int n = blockIdx.x * 8 + (tid >> 5);
  int sub = tid & 31, g = sub >> 4, l = sub & 15;
  if (n >= NN) return;
  float adn = ad2[n];
  int m = min(cnt[n], CAP);
  const int* cs = csr + (size_t)n * CAP;
  float a0 = 0.f, a1v = 0.f, ea = 0.f;
  int j = g;
  for (; j + 6 < m; j += 8) {   // per group: edges j, j+2, j+4, j+6
    int s0 = cs[j], s1 = cs[j + 2], s2 = cs[j + 4], s3 = cs[j + 6];
    float x0 = as2[s0] + adn; x0 = x0 > 0.f ? x0 : 0.2f * x0;
    float x1 = as2[s1] + adn; x1 = x1 > 0.f ? x1 : 0.2f * x1;
    float x2 = as2[s2] + adn; x2 = x2 > 0.f ? x2 : 0.2f * x2;
    float x3 = as2[s3] + adn; x3 = x3 > 0.f ? x3 : 0.2f * x3;
    u32 v0 = xs2b[(size_t)s0 * 16 + l];
    u32 v1 = xs2b[(size_t)s1 * 16 + l];
    u32 v2 = xs2b[(size_t)s2 * 16 + l];
    u32 v3 = xs2b[(size_t)s3 * 16 + l];
    float e0 = __expf(x0), e1 = __expf(x1), e2 = __expf(x2), e3 = __expf(x3);
    ea += (e0 + e1) + (e2 + e3);
    a0 += bflo(v0) * e0 + bflo(v1) * e1 + bflo(v2) * e2 + bflo(v3) * e3;
    a1v += bfhi(v0) * e0 + bfhi(v1) * e1 + bfhi(v2) * e2 + bfhi(v3) * e3;
  }
  for (; j < m; j += 2) {
    int s = cs[j];
    float al = as2[s] + adn; al = al > 0.f ? al : 0.2f * al;
    float ee = __expf(al);
    u32 v = xs2b[(size_t)s * 16 + l];
    a0 += bflo(v) * ee;
    a1v += bfhi(v) * ee;
    ea += ee;
  }
  a0 += __shfl_xor(a0, 16);
  a1v += __shfl_xor(a1v, 16);
  ea += __shfl_xor(ea, 16);
  if (g == 0) {
    float inv = 1.f / (ea + 1e-16f);
    float o0 = a0 * inv + b2[2 * l];
    float o1 = a1v * inv + b2[2 * l + 1];
    ((float2*)h2)[(size_t)n * 16 + l] = make_float2(o0, o1);
  }
}

// ---------------------------------------------------------------------------
// classifier: 8 lanes per label, float4 loads, shfl reduce
// ---------------------------------------------------------------------------
__global__ __launch_bounds__(256) void k_pred(const int* __restrict__ eli,
                                              const float* __restrict__ h2,
                                              float* __restrict__ out) {
  int gid = blockIdx.x * 256 + threadIdx.x;
  int lab = gid >> 3, q = gid & 7;
  if (lab >= NL) return;
  int a = eli[lab], b = eli[NL + lab];
  float4 va = ((const float4*)(h2 + (size_t)a * HID))[q];
  float4 vb = ((const float4*)(h2 + (size_t)b * HID))[q];
  float s = va.x * vb.x + va.y * vb.y + va.z * vb.z + va.w * vb.w;
  s += __shfl_xor(s, 1);
  s += __shfl_xor(s, 2);
  s += __shfl_xor(s, 4);
  if (q == 0) out[lab] = s;
}

extern "C" void kernel_launch(void* const* d_in, const int* in_sizes, int n_in,
                              void* d_out, int out_size, void* d_ws, size_t ws_size,
                              hipStream_t stream) {
  const float* x     = (const float*)d_in[0];
  const int*   ei    = (const int*)d_in[1];
  const int*   eli   = (const int*)d_in[2];
  const float* lin_w = (const float*)d_in[3];
  const float* lin_b = (const float*)d_in[4];
  const float* w1s   = (const float*)d_in[5];
  const float* w1d   = (const float*)d_in[6];
  const float* a1s   = (const float*)d_in[7];
  const float* a1d   = (const float*)d_in[8];
  const float* b1    = (const float*)d_in[9];
  const float* w2s   = (const float*)d_in[10];
  const float* w2d   = (const float*)d_in[11];
  const float* a2s   = (const float*)d_in[12];
  const float* a2d   = (const float*)d_in[13];
  const float* b2    = (const float*)d_in[14];
  float* out = (float*)d_out;

  char* p = (char*)d_ws;
  auto take = [&](size_t bytes) {
    char* r = p;
    p += (bytes + 255) & ~(size_t)255;
    return r;
  };
  int*   cnt  = (int*)take((size_t)NN * 4);           // zeroed per call
  int*   csr  = (int*)take((size_t)NN * CAP * 4);     // 12.8MB
  u32*   h0b  = (u32*)take((size_t)NN * 16 * 4);      // 3.2MB (bf16 pairs)
  float* as1  = (float*)take((size_t)NN * 8 * 4);
  float* ad1  = (float*)take((size_t)NN * 8 * 4);
  u32*   aggb = (u32*)take((size_t)NN * 128 * 4);     // 25.6MB (bf16 pairs)
  float* den1 = (float*)take((size_t)NN * 8 * 4);     // 1.6MB
  u32*   xs2b = (u32*)take((size_t)NN * 16 * 4);      // 3.2MB
  float* as2  = (float*)take((size_t)NN * 4);
  float* ad2  = (float*)take((size_t)NN * 4);
  float* h2   = (float*)take((size_t)NN * HID * 4);   // fp32
  float* v1s  = (float*)take(256 * 4);
  float* v1d  = (float*)take(256 * 4);
  float* v2s  = (float*)take(256 * 4);
  float* v2d  = (float*)take(256 * 4);
  uint4* w1sb = (uint4*)take(1024 * 16);              // 16KB B-frags
  uint4* w2sb = (uint4*)take(1024 * 16);              // 16KB B-frags

  const int* esrc = ei;
  const int* edst = ei + NE;

  hipMemsetAsync(cnt, 0, (size_t)NN * 4, stream);
  k_vprep<<<1, 256, 0, stream>>>(w1s, w1d, a1s, a1d, w2s, w2d, a2s, a2d,
                                 v1s, v1d, v2s, v2d, w1sb, w2sb);
  k_fill<<<(NE + 255) / 256, 256, 0, stream>>>(esrc, edst, cnt, csr);
  k_l1<<<(NN + 31) / 32, 256, 0, stream>>>(x, lin_w, lin_b, v1s, v1d,
                                           h0b, as1, ad1);
  k_aggE<<<NN / 4, 256, 0, stream>>>(cnt, csr, h0b, as1, ad1, aggb, den1);
  k_p12<<<(NN + 63) / 64, 256, 0, stream>>>(aggb, den1, w1sb, w2sb, b1,
                                            v2s, v2d, xs2b, as2, ad2);
  k_agg2<<<(NN + 7) / 8, 256, 0, stream>>>(cnt, csr, xs2b, as2, ad2, b2, h2);
  k_pred<<<(NL * 8 + 255) / 256, 256, 0, stream>>>(eli, h2, out);
}